// Round 7
// baseline (30.214 us; speedup 1.0000x reference)
//
#include <hip/hip_runtime.h>

// StructOnlyClassifier R7: two kernels, latency-overlap-oriented.
//  A) bounds_kernel: S[g] = lower_bound(batch, g). One thread per g; windowed
//     quad (int4) binary search around the prediction g*(n/B) (S[g] deviation
//     sigma <= 2048; +-6144 = 3 sigma) with deterministic widen fallback.
//     All 16K searches run concurrently -> wall ~ one probe chain.
//  B) seg_mlp_kernel: HALF-WAVE (32 lanes) per graph, 2 graphs/wave.
//     Boundaries from S (2 broadcast loads, no search). Main loop: masked
//     10-deep unrolled int4 loads -> 10 independent VMEM ops in flight per
//     lane. Over-read past segment end hits neighbors' lines (L2-resident for
//     them; ~no extra HBM). Half-local shfl reduce + MLP on both halves.

__global__ __launch_bounds__(64) void bounds_kernel(
    const int* __restrict__ batch, int* __restrict__ S, int n, int B)
{
    const int g = blockIdx.x * 64 + threadIdx.x;
    if (g > B) return;
    const long long c = (long long)g * (long long)(n / B); // predicted S[g]
    long long Wn = 6144;                                    // 3 sigma
    int lo, hi;
    for (;;) {                       // deterministic bracket (widen on miss)
        long long l = c - Wn; if (l < 0) l = 0;
        long long h = c + Wn + 3; if (h > n) h = n;
        lo = (int)l & ~3;
        hi = (int)h & ~3;            // n is a multiple of 4
        const bool okL = (lo == 0) || (batch[lo - 1] < g);
        const bool okR = (hi == n) || (batch[hi] >= g);
        if (okL && okR) break;
        Wn <<= 2;                    // widens to [0,n] worst case
    }
    // quad binary search; lo,hi stay multiples of 4, answer in [lo,hi]
    while (hi - lo > 4) {
        const int mid = ((lo + hi) >> 1) & ~3;
        const int4 q = *(const int4*)(batch + mid);
        if (q.w < g)       lo = mid + 4;
        else if (q.x >= g) hi = mid;
        else { lo = mid; hi = mid + 4; }         // straddles this quad
    }
    int ans = lo;
    if (lo < hi) {                    // hi-lo == 4: count inside final quad
        const int4 q = *(const int4*)(batch + lo);
        ans = lo + (q.x < g) + (q.y < g) + (q.z < g) + (q.w < g);
    }
    S[g] = ans;
}

constexpr int UNR = 10;   // 10*32 quads = 1280 nodes covered per half-wave

__global__ __launch_bounds__(256) void seg_mlp_kernel(
    const int* __restrict__ ntype, const int* __restrict__ S,
    const float* __restrict__ W1, const float* __restrict__ b1,
    const float* __restrict__ W2, const float* __restrict__ b2,
    const float* __restrict__ W3, const float* __restrict__ b3,
    float* __restrict__ out, int n, int B)
{
    __shared__ float sW1[128], sW2[512], sb1[32], sb2[16], sW3[16], sb3v[1];
    const int tid = threadIdx.x;
    if (tid < 128) sW1[tid] = W1[tid];
    sW2[tid]       = W2[tid];
    sW2[tid + 256] = W2[tid + 256];
    if      (tid < 32)  sb1[tid]      = b1[tid];
    else if (tid < 48)  sb2[tid - 32] = b2[tid - 32];
    else if (tid < 64)  sW3[tid - 48] = W3[tid - 48];
    else if (tid == 64) sb3v[0]       = b3[0];
    __syncthreads();

    const int lane = tid & 63;
    const int half = lane >> 5;                     // 0 or 1
    const int l32  = lane & 31;
    const int wid  = (blockIdx.x * 256 + tid) >> 6; // global wave id
    const int g    = wid * 2 + half;
    const bool valid = (g < B);
    const int gg   = valid ? g : (B - 1);

    const int s   = S[gg];
    const int e   = S[gg + 1];
    const int len = e - s;

    int c0 = 0, c1 = 0;
    int sa = (s + 3) & ~3; if (sa > e) sa = e;
    int ea = e & ~3;       if (ea < sa) ea = sa;

    {   // head scalars [s, sa): <=3 active lanes per half
        const int i = s + l32;
        if (i < sa) { const int v = ntype[i]; c0 += (v == 0); c1 += (v == 1); }
    }
    {   // main quads [sa>>2, ea>>2): masked 10-deep unroll, loads independent
        const int4* nt4 = (const int4*)ntype;
        const int nqm1 = (n >> 2) - 1;
        const int q0 = (sa >> 2) + l32;
        const int qe = (ea >> 2);
        #pragma unroll
        for (int u = 0; u < UNR; ++u) {
            const int qi = q0 + u * 32;
            const int4 v = nt4[min(qi, nqm1)];       // clamped, always issued
            if (qi < qe) {
                c0 += (v.x == 0) + (v.y == 0) + (v.z == 0) + (v.w == 0);
                c1 += (v.x == 1) + (v.y == 1) + (v.z == 1) + (v.w == 1);
            }
        }
        // pathological long-segment fallback (normally 0 iterations)
        for (int qi = q0 + UNR * 32; qi < qe; qi += 32) {
            const int4 v = nt4[qi];
            c0 += (v.x == 0) + (v.y == 0) + (v.z == 0) + (v.w == 0);
            c1 += (v.x == 1) + (v.y == 1) + (v.z == 1) + (v.w == 1);
        }
    }
    {   // tail scalars [ea, e): <=3 active lanes per half
        const int i = ea + l32;
        if (i < e) { const int v = ntype[i]; c0 += (v == 0); c1 += (v == 1); }
    }

    // half-wave reduce (xor offsets <32 stay within the half)
    unsigned long long p = (unsigned)c0 | ((unsigned long long)(unsigned)c1 << 32);
    #pragma unroll
    for (int off = 16; off; off >>= 1) p += __shfl_xor(p, off);
    const int c0t = (int)(p & 0xFFFFFFFFull);
    const int c1t = (int)(p >> 32);

    const float f0 = (float)c0t - 54.5f;
    const float f1 = (float)c1t;
    const float f2 = (float)(len - c0t - c1t);
    const float f3 = (float)len - 56.5f;

    // layer 1: unit j = l32, per half
    const int j = l32;
    float h1 = sb1[j];
    h1 = fmaf(f0, sW1[      j], h1);
    h1 = fmaf(f1, sW1[ 32 + j], h1);
    h1 = fmaf(f2, sW1[ 64 + j], h1);
    h1 = fmaf(f3, sW1[ 96 + j], h1);
    h1 = fmaxf(0.0f, h1);

    // layer 2: unit m = lane&15 (dup within half), h1 broadcast half-locally
    const int m = lane & 15;
    const int hbase = lane & 32;
    float s2 = sb2[m];
    #pragma unroll
    for (int jj = 0; jj < 32; ++jj)
        s2 = fmaf(__shfl(h1, hbase + jj), sW2[jj * 16 + m], s2);
    const float h2 = fmaxf(0.0f, s2);

    // layer 3: reduce 16 units within the 16-lane group
    float p3 = h2 * sW3[m];
    p3 += __shfl_xor(p3, 8);
    p3 += __shfl_xor(p3, 4);
    p3 += __shfl_xor(p3, 2);
    p3 += __shfl_xor(p3, 1);

    if (valid && l32 == 0) out[g] = p3 + sb3v[0];
}

extern "C" void kernel_launch(void* const* d_in, const int* in_sizes, int n_in,
                              void* d_out, int out_size, void* d_ws, size_t ws_size,
                              hipStream_t stream) {
    // inputs: 0:x(N) 1:batch(N) 2:node_type(N) 3:num_graphs 4:W1 5:b1 6:W2 7:b2 8:W3 9:b3
    const int*   batch = (const int*)d_in[1];
    const int*   ntype = (const int*)d_in[2];
    const float* W1    = (const float*)d_in[4];
    const float* b1    = (const float*)d_in[5];
    const float* W2    = (const float*)d_in[6];
    const float* b2    = (const float*)d_in[7];
    const float* W3    = (const float*)d_in[8];
    const float* b3    = (const float*)d_in[9];
    float*       out   = (float*)d_out;

    const int n = in_sizes[1];          // 16,777,216 nodes
    const int B = out_size;             // 16,384 graphs

    int* S = (int*)d_ws;                // B+1 ints

    bounds_kernel<<<(B + 1 + 63) / 64, 64, 0, stream>>>(batch, S, n, B);

    const int waves  = (B + 1) / 2;                  // 8192 (2 graphs/wave)
    const int blocks = (waves * 64 + 255) / 256;     // 2048
    seg_mlp_kernel<<<blocks, 256, 0, stream>>>(
        ntype, S, W1, b1, W2, b2, W3, b3, out, n, B);
}